// Round 8
// baseline (215.589 us; speedup 1.0000x reference)
//
#include <hip/hip_runtime.h>
#include <math.h>

#define ALPHA 32.0f
#define MRG 0.1f
#define STAT_WEIGHT 0.01f
#define STAT_ADJ_W 0.15f
#define COS_EPS 1e-8f

typedef __attribute__((ext_vector_type(8))) short bf16x8;
typedef __attribute__((ext_vector_type(4))) float f32x4;
typedef __attribute__((ext_vector_type(4))) unsigned int u32x4;

__device__ __forceinline__ ushort f2bf(float f) {
    unsigned u = __float_as_uint(f);
    return (ushort)((u + 0x7FFFu + ((u >> 16) & 1u)) >> 16);   // RNE
}
__device__ __forceinline__ unsigned pk2(float a, float b) {
    return (unsigned)f2bf(a) | ((unsigned)f2bf(b) << 16);
}

// block-wide (128 threads = 2 waves) sum reduce, result broadcast to all
__device__ __forceinline__ float bred128(float v, float* sm, int d) {
    #pragma unroll
    for (int off = 1; off < 64; off <<= 1) v += __shfl_xor(v, off);
    if ((d & 63) == 0) sm[d >> 6] = v;
    __syncthreads();
    float r = sm[0] + sm[1];
    __syncthreads();
    return r;
}

// ---------------- K1: per-sample stats; writes Xn16 row b, adj[c], num_valid ---
__global__ void k_stats(const float* __restrict__ X, const float* __restrict__ proxies,
                        const float* __restrict__ cc, const int* __restrict__ T,
                        ushort* __restrict__ Xn16, float* __restrict__ adj,
                        float* __restrict__ scal, int B) {
    const int b = blockIdx.x, d = threadIdx.x;   // d in [0,128)
    __shared__ int Tl[512];
    __shared__ float sm[2];
    for (int i = d; i < B; i += 128) Tl[i] = T[i];
    __syncthreads();
    const int c = Tl[b];

    float p  = proxies[(size_t)c * 128 + d];
    float cv = cc[(size_t)c * 128 + d];
    float s2 = bred128(p * p, sm, d);
    float c2 = bred128(cv * cv, sm, d);
    float pc = bred128(p * cv, sm, d);

    float sd = 0.f, qd = 0.f;
    int cnt = 0, minj = -1;
    for (int j = 0; j < B; ++j) {
        if (Tl[j] == c) {                      // block-uniform branch
            float x = X[(size_t)j * 128 + d];
            float n2 = bred128(x * x, sm, d);
            float xn = x * rsqrtf(n2 + 1e-12f);
            sd += xn; qd += xn * xn;
            if (j == b) Xn16[(size_t)b * 128 + d] = f2bf(xn);
            if (minj < 0) minj = j;
            ++cnt;
        }
    }
    float fc = (float)cnt;
    float m = sd / fc;
    float var = fminf(fmaxf(qd / fc - m * m, 1e-6f), 10.0f);
    float sv = bred128(var, sm, d);
    if (d == 0) {
        float inv = rsqrtf(s2 + 1e-12f);
        float pn = fmaxf(sqrtf(s2) * inv, COS_EPS);
        float cn = fmaxf(sqrtf(c2), COS_EPS);
        float censim = (pc * inv) / (pn * cn);
        float vw = 1.0f / (1.0f + sv * (1.0f / 128.0f));
        adj[c] = censim * vw * STAT_ADJ_W;
        if (minj == b) atomicAdd(&scal[3], 1.0f);
    }
}

// ---------------- K2: orientation-A GEMM, 64 classes/block, dual-tile ILP ------
// 782 blocks x 64 classes -> ~3 waves/SIMD. Wave owns ONE 16-class tile
// (bfr[4] = 16 VGPRs), sweeps all 512 rows as 16 iterations x 2 row-tiles
// (8 b128 loads in flight, 2 independent MFMA chains). Full fusion: pos/neg
// complete in-block, adj via gated post-hoc exp factor, cc-abs folded in.
__launch_bounds__(256, 3)
__global__ void k_main(const float* __restrict__ proxies, const float* __restrict__ cc,
                       const ushort* __restrict__ Xn16, const int* __restrict__ T,
                       const float* __restrict__ adj, float* __restrict__ scal,
                       float* __restrict__ out, int C, int nblk) {
    const int tid = threadIdx.x, lane = tid & 63, wv = tid >> 6;
    const int nlo = lane & 15, quad = lane >> 4;
    const int c0 = blockIdx.x * 64;

    __shared__ int Tl[512];
    __shared__ float red[4][3];
    Tl[tid] = T[tid];
    Tl[tid + 256] = T[tid + 256];

    // ---- cc |.| partial for this block's 64-class slice ----
    float cabs = 0.f;
    {
        const int n4 = ((c0 + 64 <= C) ? 64 : (C - c0)) * 32;
        const float4* cp = (const float4*)(cc + (size_t)c0 * 128);
        for (int i = tid; i < n4; i += 256) {
            float4 v = cp[i];
            cabs += fabsf(v.x) + fabsf(v.y) + fabsf(v.z) + fabsf(v.w);
        }
    }

    // ---- B fragments: wave's 16-class tile, normalized in-register ----
    const int cls = c0 + wv * 16 + nlo;
    const int cl = (cls < C) ? cls : C - 1;
    bf16x8 bfr[4];
    {
        const float4* pr = (const float4*)(proxies + (size_t)cl * 128);
        float4 v0[4], v1[4];
        float s2 = 0.f;
        #pragma unroll
        for (int ks = 0; ks < 4; ++ks) {
            v0[ks] = pr[ks * 8 + quad * 2];
            v1[ks] = pr[ks * 8 + quad * 2 + 1];
            s2 += v0[ks].x*v0[ks].x + v0[ks].y*v0[ks].y + v0[ks].z*v0[ks].z + v0[ks].w*v0[ks].w
                + v1[ks].x*v1[ks].x + v1[ks].y*v1[ks].y + v1[ks].z*v1[ks].z + v1[ks].w*v1[ks].w;
        }
        s2 += __shfl_xor(s2, 16);
        s2 += __shfl_xor(s2, 32);
        float pin = rsqrtf(s2 + 1e-12f);
        #pragma unroll
        for (int ks = 0; ks < 4; ++ks) {
            u32x4 u;
            u.x = pk2(v0[ks].x * pin, v0[ks].y * pin);
            u.y = pk2(v0[ks].z * pin, v0[ks].w * pin);
            u.z = pk2(v1[ks].x * pin, v1[ks].y * pin);
            u.w = pk2(v1[ks].z * pin, v1[ks].w * pin);
            bfr[ks] = __builtin_bit_cast(bf16x8, u);
        }
    }
    __syncthreads();   // Tl ready

    // ---- sweep all 512 rows: 16 iterations x 2 row-tiles ----
    float pp = 0.f, np = 0.f;
    const ushort* xbase = Xn16 + (size_t)nlo * 128 + quad * 8;
    for (int it = 0; it < 16; ++it) {
        const ushort* xr0 = xbase + (size_t)it * 4096;   // rows it*32 .. +15
        const ushort* xr1 = xr0 + 2048;                  // rows it*32+16 .. +31
        u32x4 a00 = *(const u32x4*)(xr0);
        u32x4 a10 = *(const u32x4*)(xr1);
        u32x4 a01 = *(const u32x4*)(xr0 + 32);
        u32x4 a11 = *(const u32x4*)(xr1 + 32);
        u32x4 a02 = *(const u32x4*)(xr0 + 64);
        u32x4 a12 = *(const u32x4*)(xr1 + 64);
        u32x4 a03 = *(const u32x4*)(xr0 + 96);
        u32x4 a13 = *(const u32x4*)(xr1 + 96);
        f32x4 acc0 = {0.f,0.f,0.f,0.f}, acc1 = {0.f,0.f,0.f,0.f};
        acc0 = __builtin_amdgcn_mfma_f32_16x16x32_bf16(__builtin_bit_cast(bf16x8, a00), bfr[0], acc0, 0, 0, 0);
        acc1 = __builtin_amdgcn_mfma_f32_16x16x32_bf16(__builtin_bit_cast(bf16x8, a10), bfr[0], acc1, 0, 0, 0);
        acc0 = __builtin_amdgcn_mfma_f32_16x16x32_bf16(__builtin_bit_cast(bf16x8, a01), bfr[1], acc0, 0, 0, 0);
        acc1 = __builtin_amdgcn_mfma_f32_16x16x32_bf16(__builtin_bit_cast(bf16x8, a11), bfr[1], acc1, 0, 0, 0);
        acc0 = __builtin_amdgcn_mfma_f32_16x16x32_bf16(__builtin_bit_cast(bf16x8, a02), bfr[2], acc0, 0, 0, 0);
        acc1 = __builtin_amdgcn_mfma_f32_16x16x32_bf16(__builtin_bit_cast(bf16x8, a12), bfr[2], acc1, 0, 0, 0);
        acc0 = __builtin_amdgcn_mfma_f32_16x16x32_bf16(__builtin_bit_cast(bf16x8, a03), bfr[3], acc0, 0, 0, 0);
        acc1 = __builtin_amdgcn_mfma_f32_16x16x32_bf16(__builtin_bit_cast(bf16x8, a13), bfr[3], acc1, 0, 0, 0);

        int4 t40 = *(const int4*)&Tl[it * 32 + quad * 4];
        int4 t41 = *(const int4*)&Tl[it * 32 + 16 + quad * 4];
        int tv0[4] = {t40.x, t40.y, t40.z, t40.w};
        int tv1[4] = {t41.x, t41.y, t41.z, t41.w};
        // rare-positive epilogue: hot path = fma + exp + add (+cmp)
        #pragma unroll
        for (int r = 0; r < 4; ++r) {
            {
                float v = acc0[r];
                float e = __expf(fmaf(ALPHA, v, ALPHA * MRG));
                np += e;
                if (tv0[r] == cls) {             // ~1 in 50k: exec-mask skipped
                    np -= e;
                    pp += __expf(-ALPHA * (v - MRG));
                }
            }
            {
                float v = acc1[r];
                float e = __expf(fmaf(ALPHA, v, ALPHA * MRG));
                np += e;
                if (tv1[r] == cls) {
                    np -= e;
                    pp += __expf(-ALPHA * (v - MRG));
                }
            }
        }
    }

    // ---- per-class totals across quads; adj factor; log1p ----
    pp += __shfl_xor(pp, 16); pp += __shfl_xor(pp, 32);
    np += __shfl_xor(np, 16); np += __shfl_xor(np, 32);

    float lp = 0.f, ln = 0.f;
    {
        float a = adj[cl];                       // gated below; garbage-safe
        float as = (pp > 0.f) ? a : 0.f;         // absent class => adj = 0
        if (cls < C) {
            lp = log1pf(pp * __expf(-ALPHA * as));
            ln = log1pf(np * __expf( ALPHA * as));
        }
    }
    // quads hold identical values; sum across nlo (every lane ends with tile sum)
    #pragma unroll
    for (int off = 1; off < 16; off <<= 1) {
        lp += __shfl_xor(lp, off);
        ln += __shfl_xor(ln, off);
    }
    #pragma unroll
    for (int off = 1; off < 64; off <<= 1) cabs += __shfl_xor(cabs, off);

    if (lane == 0) { red[wv][0] = lp; red[wv][1] = ln; red[wv][2] = cabs; }
    __syncthreads();
    if (tid == 0) {
        atomicAdd(&scal[0], red[0][0] + red[1][0] + red[2][0] + red[3][0]);
        atomicAdd(&scal[1], red[0][1] + red[1][1] + red[2][1] + red[3][1]);
        atomicAdd(&scal[2], red[0][2] + red[1][2] + red[2][2] + red[3][2]);
        __threadfence();
        unsigned old = atomicAdd((unsigned*)(scal + 4), 1u);
        if (old == (unsigned)(nblk - 1)) {
            float S0 = atomicAdd(&scal[0], 0.f);
            float S1 = atomicAdd(&scal[1], 0.f);
            float S2 = atomicAdd(&scal[2], 0.f);
            float S3 = atomicAdd(&scal[3], 0.f);
            out[0] = S0 / S3 + S1 / (float)C + STAT_WEIGHT * (S2 / ((float)C * 128.f));
        }
    }
}

extern "C" void kernel_launch(void* const* d_in, const int* in_sizes, int n_in,
                              void* d_out, int out_size, void* d_ws, size_t ws_size,
                              hipStream_t stream) {
    const float* X       = (const float*)d_in[0];
    const int*   T       = (const int*)d_in[1];
    const float* proxies = (const float*)d_in[2];
    const float* cc      = (const float*)d_in[3];
    float* out = (float*)d_out;

    const int B = in_sizes[1];            // 512
    const int D = in_sizes[0] / B;        // 128
    const int C = in_sizes[2] / D;        // 50000

    float*  adj  = (float*)d_ws;                       // C (only present classes written/read)
    float*  scal = adj + C;                            // 8 (zeroed)
    ushort* Xn16 = (ushort*)(scal + 8);                // B*D bf16

    const int nblk = (C + 63) / 64;                    // 782

    (void)hipMemsetAsync(scal, 0, 8 * sizeof(float), stream);
    k_stats<<<B, 128, 0, stream>>>(X, proxies, cc, T, Xn16, adj, scal, B);
    k_main<<<nblk, 256, 0, stream>>>(proxies, cc, Xn16, T, adj, scal, out, C, nblk);
}

// Round 9
// 199.809 us; speedup vs baseline: 1.0790x; 1.0790x over previous
//
#include <hip/hip_runtime.h>
#include <math.h>

#define ALPHA 32.0f
#define MRG 0.1f
#define STAT_WEIGHT 0.01f
#define STAT_ADJ_W 0.15f
#define COS_EPS 1e-8f

typedef __attribute__((ext_vector_type(8))) short bf16x8;
typedef __attribute__((ext_vector_type(4))) float f32x4;
typedef __attribute__((ext_vector_type(4))) unsigned int u32x4;

__device__ __forceinline__ ushort f2bf(float f) {
    unsigned u = __float_as_uint(f);
    return (ushort)((u + 0x7FFFu + ((u >> 16) & 1u)) >> 16);   // RNE
}
__device__ __forceinline__ unsigned pk2(float a, float b) {
    return (unsigned)f2bf(a) | ((unsigned)f2bf(b) << 16);
}

// block-wide (128 threads = 2 waves) sum reduce, result broadcast to all
__device__ __forceinline__ float bred128(float v, float* sm, int d) {
    #pragma unroll
    for (int off = 1; off < 64; off <<= 1) v += __shfl_xor(v, off);
    if ((d & 63) == 0) sm[d >> 6] = v;
    __syncthreads();
    float r = sm[0] + sm[1];
    __syncthreads();
    return r;
}

// ---------------- K1: per-sample stats; writes Xn16 row b, adj[c], num_valid ---
__global__ void k_stats(const float* __restrict__ X, const float* __restrict__ proxies,
                        const float* __restrict__ cc, const int* __restrict__ T,
                        ushort* __restrict__ Xn16, float* __restrict__ adj,
                        float* __restrict__ scal, int B) {
    const int b = blockIdx.x, d = threadIdx.x;   // d in [0,128)
    __shared__ int Tl[512];
    __shared__ float sm[2];
    for (int i = d; i < B; i += 128) Tl[i] = T[i];
    __syncthreads();
    const int c = Tl[b];

    float p  = proxies[(size_t)c * 128 + d];
    float cv = cc[(size_t)c * 128 + d];
    float s2 = bred128(p * p, sm, d);
    float c2 = bred128(cv * cv, sm, d);
    float pc = bred128(p * cv, sm, d);

    float sd = 0.f, qd = 0.f;
    int cnt = 0, minj = -1;
    for (int j = 0; j < B; ++j) {
        if (Tl[j] == c) {                      // block-uniform branch
            float x = X[(size_t)j * 128 + d];
            float n2 = bred128(x * x, sm, d);
            float xn = x * rsqrtf(n2 + 1e-12f);
            sd += xn; qd += xn * xn;
            if (j == b) Xn16[(size_t)b * 128 + d] = f2bf(xn);
            if (minj < 0) minj = j;
            ++cnt;
        }
    }
    float fc = (float)cnt;
    float m = sd / fc;
    float var = fminf(fmaxf(qd / fc - m * m, 1e-6f), 10.0f);
    float sv = bred128(var, sm, d);
    if (d == 0) {
        float inv = rsqrtf(s2 + 1e-12f);
        float pn = fmaxf(sqrtf(s2) * inv, COS_EPS);
        float cn = fmaxf(sqrtf(c2), COS_EPS);
        float censim = (pc * inv) / (pn * cn);
        float vw = 1.0f / (1.0f + sv * (1.0f / 128.0f));
        adj[c] = censim * vw * STAT_ADJ_W;
        if (minj == b) atomicAdd(&scal[3], 1.0f);
    }
}

// ---------------- K2: orientation-A GEMM, row-split waves ----------------------
// 782 blocks x 64 classes (~3 blocks/CU). Wave shape = r7's proven optimum:
// 2 class-tiles (bfr[2][4]=32 VGPR), 4 b128 A-loads -> 8 MFMAs per iteration.
// Row parallelism: wv>>1 picks the 256-row half, wv&1 the 32-class group.
// Halves combine per-class pos/neg via LDS before log1p (present-gate on the
// COMBINED sum). Full fusion retained: cc-abs + adj factor + finalize.
__launch_bounds__(256, 4)
__global__ void k_main(const float* __restrict__ proxies, const float* __restrict__ cc,
                       const ushort* __restrict__ Xn16, const int* __restrict__ T,
                       const float* __restrict__ adj, float* __restrict__ scal,
                       float* __restrict__ out, int C, int nblk) {
    const int tid = threadIdx.x, lane = tid & 63, wv = tid >> 6;
    const int nlo = lane & 15, quad = lane >> 4;
    const int c0 = blockIdx.x * 64;
    const int cgrp = wv & 1;          // which 32-class group
    const int rh   = wv >> 1;         // which 256-row half

    __shared__ int Tl[512];
    __shared__ float Pv[4][32], Nv[4][32];
    __shared__ float red[4][3];
    Tl[tid] = T[tid];
    Tl[tid + 256] = T[tid + 256];

    // ---- cc |.| partial for this block's 64-class slice ----
    float cabs = 0.f;
    {
        const int n4 = ((c0 + 64 <= C) ? 64 : (C - c0)) * 32;
        const float4* cp = (const float4*)(cc + (size_t)c0 * 128);
        for (int i = tid; i < n4; i += 256) {
            float4 v = cp[i];
            cabs += fabsf(v.x) + fabsf(v.y) + fabsf(v.z) + fabsf(v.w);
        }
    }

    // ---- B fragments: 2 class-tiles, normalized in-register (r7 shape) ----
    const int cls0 = c0 + cgrp * 32 + nlo;
    const int cls1 = cls0 + 16;
    bf16x8 bfr[2][4];
    #pragma unroll
    for (int t = 0; t < 2; ++t) {
        int cls = c0 + cgrp * 32 + t * 16 + nlo;
        int cl = (cls < C) ? cls : C - 1;
        const float4* pr = (const float4*)(proxies + (size_t)cl * 128);
        float4 v0[4], v1[4];
        float s2 = 0.f;
        #pragma unroll
        for (int ks = 0; ks < 4; ++ks) {
            v0[ks] = pr[ks * 8 + quad * 2];
            v1[ks] = pr[ks * 8 + quad * 2 + 1];
            s2 += v0[ks].x*v0[ks].x + v0[ks].y*v0[ks].y + v0[ks].z*v0[ks].z + v0[ks].w*v0[ks].w
                + v1[ks].x*v1[ks].x + v1[ks].y*v1[ks].y + v1[ks].z*v1[ks].z + v1[ks].w*v1[ks].w;
        }
        s2 += __shfl_xor(s2, 16);
        s2 += __shfl_xor(s2, 32);
        float pin = rsqrtf(s2 + 1e-12f);
        #pragma unroll
        for (int ks = 0; ks < 4; ++ks) {
            u32x4 u;
            u.x = pk2(v0[ks].x * pin, v0[ks].y * pin);
            u.y = pk2(v0[ks].z * pin, v0[ks].w * pin);
            u.z = pk2(v1[ks].x * pin, v1[ks].y * pin);
            u.w = pk2(v1[ks].z * pin, v1[ks].w * pin);
            bfr[t][ks] = __builtin_bit_cast(bf16x8, u);
        }
    }
    __syncthreads();   // Tl ready

    // ---- sweep this wave's 256 rows: 16 row-tiles, 4 loads -> 8 MFMAs ----
    float pp0 = 0.f, pp1 = 0.f, np0 = 0.f, np1 = 0.f;
    const ushort* xbase = Xn16 + (size_t)(rh * 256 + nlo) * 128 + quad * 8;
    #pragma unroll 2
    for (int rt = 0; rt < 16; ++rt) {
        const ushort* xr = xbase + (size_t)rt * 16 * 128;
        u32x4 af0 = *(const u32x4*)(xr);
        u32x4 af1 = *(const u32x4*)(xr + 32);
        u32x4 af2 = *(const u32x4*)(xr + 64);
        u32x4 af3 = *(const u32x4*)(xr + 96);
        f32x4 acc0 = {0.f,0.f,0.f,0.f}, acc1 = {0.f,0.f,0.f,0.f};
        acc0 = __builtin_amdgcn_mfma_f32_16x16x32_bf16(__builtin_bit_cast(bf16x8, af0), bfr[0][0], acc0, 0, 0, 0);
        acc1 = __builtin_amdgcn_mfma_f32_16x16x32_bf16(__builtin_bit_cast(bf16x8, af0), bfr[1][0], acc1, 0, 0, 0);
        acc0 = __builtin_amdgcn_mfma_f32_16x16x32_bf16(__builtin_bit_cast(bf16x8, af1), bfr[0][1], acc0, 0, 0, 0);
        acc1 = __builtin_amdgcn_mfma_f32_16x16x32_bf16(__builtin_bit_cast(bf16x8, af1), bfr[1][1], acc1, 0, 0, 0);
        acc0 = __builtin_amdgcn_mfma_f32_16x16x32_bf16(__builtin_bit_cast(bf16x8, af2), bfr[0][2], acc0, 0, 0, 0);
        acc1 = __builtin_amdgcn_mfma_f32_16x16x32_bf16(__builtin_bit_cast(bf16x8, af2), bfr[1][2], acc1, 0, 0, 0);
        acc0 = __builtin_amdgcn_mfma_f32_16x16x32_bf16(__builtin_bit_cast(bf16x8, af3), bfr[0][3], acc0, 0, 0, 0);
        acc1 = __builtin_amdgcn_mfma_f32_16x16x32_bf16(__builtin_bit_cast(bf16x8, af3), bfr[1][3], acc1, 0, 0, 0);

        int4 t4 = *(const int4*)&Tl[rh * 256 + rt * 16 + quad * 4];
        int tvs[4] = {t4.x, t4.y, t4.z, t4.w};
        #pragma unroll
        for (int r = 0; r < 4; ++r) {
            { bool po = (tvs[r] == cls0); float v = acc0[r];
              float e = __expf(po ? -ALPHA * (v - MRG) : ALPHA * (v + MRG));
              pp0 += po ? e : 0.f; np0 += po ? 0.f : e; }
            { bool po = (tvs[r] == cls1); float v = acc1[r];
              float e = __expf(po ? -ALPHA * (v - MRG) : ALPHA * (v + MRG));
              pp1 += po ? e : 0.f; np1 += po ? 0.f : e; }
        }
    }

    // ---- per-class sums across quads, exchange row-halves via LDS ----
    pp0 += __shfl_xor(pp0, 16); pp0 += __shfl_xor(pp0, 32);
    np0 += __shfl_xor(np0, 16); np0 += __shfl_xor(np0, 32);
    pp1 += __shfl_xor(pp1, 16); pp1 += __shfl_xor(pp1, 32);
    np1 += __shfl_xor(np1, 16); np1 += __shfl_xor(np1, 32);
    if (lane < 16) {
        Pv[wv][lane] = pp0; Pv[wv][lane + 16] = pp1;
        Nv[wv][lane] = np0; Nv[wv][lane + 16] = np1;
    }
    __syncthreads();

    // waves 0,1 combine with waves 2,3 (same classes, other row half)
    float lp = 0.f, ln = 0.f;
    if (wv < 2 && lane < 32) {
        int cls2 = c0 + wv * 32 + lane;
        if (cls2 < C) {
            float ps = Pv[wv][lane] + Pv[wv + 2][lane];
            float ns = Nv[wv][lane] + Nv[wv + 2][lane];
            float a = adj[cls2];                 // gated below; garbage-safe
            float as = (ps > 0.f) ? a : 0.f;     // absent class => adj = 0
            lp = log1pf(ps * __expf(-ALPHA * as));
            ln = log1pf(ns * __expf( ALPHA * as));
        }
    }
    #pragma unroll
    for (int off = 1; off < 64; off <<= 1) {
        lp += __shfl_xor(lp, off);
        ln += __shfl_xor(ln, off);
        cabs += __shfl_xor(cabs, off);
    }
    if (lane == 0) { red[wv][0] = lp; red[wv][1] = ln; red[wv][2] = cabs; }
    __syncthreads();
    if (tid == 0) {
        atomicAdd(&scal[0], red[0][0] + red[1][0] + red[2][0] + red[3][0]);
        atomicAdd(&scal[1], red[0][1] + red[1][1] + red[2][1] + red[3][1]);
        atomicAdd(&scal[2], red[0][2] + red[1][2] + red[2][2] + red[3][2]);
        __threadfence();
        unsigned old = atomicAdd((unsigned*)(scal + 4), 1u);
        if (old == (unsigned)(nblk - 1)) {
            float S0 = atomicAdd(&scal[0], 0.f);
            float S1 = atomicAdd(&scal[1], 0.f);
            float S2 = atomicAdd(&scal[2], 0.f);
            float S3 = atomicAdd(&scal[3], 0.f);
            out[0] = S0 / S3 + S1 / (float)C + STAT_WEIGHT * (S2 / ((float)C * 128.f));
        }
    }
}

extern "C" void kernel_launch(void* const* d_in, const int* in_sizes, int n_in,
                              void* d_out, int out_size, void* d_ws, size_t ws_size,
                              hipStream_t stream) {
    const float* X       = (const float*)d_in[0];
    const int*   T       = (const int*)d_in[1];
    const float* proxies = (const float*)d_in[2];
    const float* cc      = (const float*)d_in[3];
    float* out = (float*)d_out;

    const int B = in_sizes[1];            // 512
    const int D = in_sizes[0] / B;        // 128
    const int C = in_sizes[2] / D;        // 50000

    float*  adj  = (float*)d_ws;                       // C (only present classes written/read)
    float*  scal = adj + C;                            // 8 (zeroed)
    ushort* Xn16 = (ushort*)(scal + 8);                // B*D bf16

    const int nblk = (C + 63) / 64;                    // 782

    (void)hipMemsetAsync(scal, 0, 8 * sizeof(float), stream);
    k_stats<<<B, 128, 0, stream>>>(X, proxies, cc, T, Xn16, adj, scal, B);
    k_main<<<nblk, 256, 0, stream>>>(proxies, cc, Xn16, T, adj, scal, out, C, nblk);
}

// Round 10
// 161.572 us; speedup vs baseline: 1.3343x; 1.2367x over previous
//
#include <hip/hip_runtime.h>
#include <math.h>

#define ALPHA 32.0f
#define MRG 0.1f
#define STAT_WEIGHT 0.01f
#define STAT_ADJ_W 0.15f
#define COS_EPS 1e-8f

typedef __attribute__((ext_vector_type(8))) short bf16x8;
typedef __attribute__((ext_vector_type(4))) float f32x4;
typedef __attribute__((ext_vector_type(4))) unsigned int u32x4;

__device__ __forceinline__ ushort f2bf(float f) {
    unsigned u = __float_as_uint(f);
    return (ushort)((u + 0x7FFFu + ((u >> 16) & 1u)) >> 16);   // RNE
}
__device__ __forceinline__ unsigned pk2(float a, float b) {
    return (unsigned)f2bf(a) | ((unsigned)f2bf(b) << 16);
}

// block-wide (128 threads = 2 waves) sum reduce, result broadcast to all
__device__ __forceinline__ float bred128(float v, float* sm, int d) {
    #pragma unroll
    for (int off = 1; off < 64; off <<= 1) v += __shfl_xor(v, off);
    if ((d & 63) == 0) sm[d >> 6] = v;
    __syncthreads();
    float r = sm[0] + sm[1];
    __syncthreads();
    return r;
}

// ---------------- K1: per-sample stats; writes SWIZZLED Xn16 row, adj, n_valid -
// Swizzle: 16-byte group g of row b stored at group g ^ (b & 15). This makes
// k_main's LDS fragment reads bank-spread after a plain contiguous copy.
__global__ void k_stats(const float* __restrict__ X, const float* __restrict__ proxies,
                        const float* __restrict__ cc, const int* __restrict__ T,
                        ushort* __restrict__ Xn16, float* __restrict__ adj,
                        float* __restrict__ scal, int B) {
    const int b = blockIdx.x, d = threadIdx.x;   // d in [0,128) == k index
    __shared__ int Tl[512];
    __shared__ float sm[2];
    for (int i = d; i < B; i += 128) Tl[i] = T[i];
    __syncthreads();
    const int c = Tl[b];

    float p  = proxies[(size_t)c * 128 + d];
    float cv = cc[(size_t)c * 128 + d];
    float s2 = bred128(p * p, sm, d);
    float c2 = bred128(cv * cv, sm, d);
    float pc = bred128(p * cv, sm, d);

    const int pk = ((((d >> 3) ^ (b & 15)) << 3) | (d & 7));   // swizzled column

    float sd = 0.f, qd = 0.f;
    int cnt = 0, minj = -1;
    for (int j = 0; j < B; ++j) {
        if (Tl[j] == c) {                      // block-uniform branch
            float x = X[(size_t)j * 128 + d];
            float n2 = bred128(x * x, sm, d);
            float xn = x * rsqrtf(n2 + 1e-12f);
            sd += xn; qd += xn * xn;
            if (j == b) Xn16[(size_t)b * 128 + pk] = f2bf(xn);
            if (minj < 0) minj = j;
            ++cnt;
        }
    }
    float fc = (float)cnt;
    float m = sd / fc;
    float var = fminf(fmaxf(qd / fc - m * m, 1e-6f), 10.0f);
    float sv = bred128(var, sm, d);
    if (d == 0) {
        float inv = rsqrtf(s2 + 1e-12f);
        float pn = fmaxf(sqrtf(s2) * inv, COS_EPS);
        float cn = fmaxf(sqrtf(c2), COS_EPS);
        float censim = (pc * inv) / (pn * cn);
        float vw = 1.0f / (1.0f + sv * (1.0f / 128.0f));
        adj[c] = censim * vw * STAT_ADJ_W;
        if (minj == b) atomicAdd(&scal[3], 1.0f);
    }
}

// ---------------- K2: LDS-staged A (double-buffered), register B ---------------
// 391 blocks x 128 classes. Wave owns 2 class-tiles (bfr[2][4]=32 VGPR, proven
// no-spill shape) and all 512 rows. A staged cooperatively: 8 chunks x 64 rows
// (16 KB), double-buffered, loads for chunk+2 issued during chunk, ds_writes
// for chunk+1 before computing chunk, ONE barrier per chunk. Fragment ds_reads
// hit the source-swizzled layout -> bank-spread. Full fusion retained.
__launch_bounds__(256, 2)
__global__ void k_main(const float* __restrict__ proxies, const float* __restrict__ cc,
                       const ushort* __restrict__ Xsw, const int* __restrict__ T,
                       const float* __restrict__ adj, float* __restrict__ scal,
                       float* __restrict__ out, int C, int nblk) {
    const int tid = threadIdx.x, lane = tid & 63, wv = tid >> 6;
    const int nlo = lane & 15, quad = lane >> 4;
    const int c0 = blockIdx.x * 128;

    __shared__ ushort Sx[16384];      // 2 x 16 KB double buffer
    __shared__ int Tl[512];
    __shared__ float red[4][3];
    Tl[tid] = T[tid];
    Tl[tid + 256] = T[tid + 256];

    // ---- cc |.| partial for this block's 128-class slice ----
    float cabs = 0.f;
    {
        const int n4 = ((c0 + 128 <= C) ? 128 : (C - c0)) * 32;
        const float4* cp = (const float4*)(cc + (size_t)c0 * 128);
        for (int i = tid; i < n4; i += 256) {
            float4 v = cp[i];
            cabs += fabsf(v.x) + fabsf(v.y) + fabsf(v.z) + fabsf(v.w);
        }
    }

    // ---- B fragments: 2 class-tiles, normalized in-register (proven shape) ----
    const int cls0 = c0 + wv * 32 + nlo;
    const int cls1 = cls0 + 16;
    bf16x8 bfr[2][4];
    #pragma unroll
    for (int t = 0; t < 2; ++t) {
        int cls = c0 + wv * 32 + t * 16 + nlo;
        int cl = (cls < C) ? cls : C - 1;
        const float4* pr = (const float4*)(proxies + (size_t)cl * 128);
        float4 v0[4], v1[4];
        float s2 = 0.f;
        #pragma unroll
        for (int ks = 0; ks < 4; ++ks) {
            v0[ks] = pr[ks * 8 + quad * 2];
            v1[ks] = pr[ks * 8 + quad * 2 + 1];
            s2 += v0[ks].x*v0[ks].x + v0[ks].y*v0[ks].y + v0[ks].z*v0[ks].z + v0[ks].w*v0[ks].w
                + v1[ks].x*v1[ks].x + v1[ks].y*v1[ks].y + v1[ks].z*v1[ks].z + v1[ks].w*v1[ks].w;
        }
        s2 += __shfl_xor(s2, 16);
        s2 += __shfl_xor(s2, 32);
        float pin = rsqrtf(s2 + 1e-12f);
        #pragma unroll
        for (int ks = 0; ks < 4; ++ks) {
            u32x4 u;
            u.x = pk2(v0[ks].x * pin, v0[ks].y * pin);
            u.y = pk2(v0[ks].z * pin, v0[ks].w * pin);
            u.z = pk2(v1[ks].x * pin, v1[ks].y * pin);
            u.w = pk2(v1[ks].z * pin, v1[ks].w * pin);
            bfr[t][ks] = __builtin_bit_cast(bf16x8, u);
        }
    }

    // ---- fragment LDS offsets (in ushorts); swizzle index is nlo ----
    int fro[4];
    #pragma unroll
    for (int ks = 0; ks < 4; ++ks)
        fro[ks] = nlo * 128 + (((ks * 4 + quad) ^ nlo) << 3);

    // ---- staging pipeline: chunk = 64 rows = 16 KB = 1024 uint4 ----
    const uint4* gX = (const uint4*)Xsw;
    uint4 s0, s1, s2v, s3;
    #define LOADV(ch) { const uint4* p_ = gX + (ch) * 1024 + tid; \
                        s0 = p_[0]; s1 = p_[256]; s2v = p_[512]; s3 = p_[768]; }
    #define WRITEV(bi) { uint4* q_ = (uint4*)&Sx[(bi) * 8192]; \
                         q_[tid] = s0; q_[tid + 256] = s1; q_[tid + 512] = s2v; q_[tid + 768] = s3; }
    LOADV(0); WRITEV(0); LOADV(1);
    __syncthreads();

    float pp0 = 0.f, np0 = 0.f, pp1 = 0.f, np1 = 0.f;
    for (int chunk = 0; chunk < 8; ++chunk) {
        const int bo = (chunk & 1) * 8192;
        if (chunk < 7) {
            WRITEV((chunk + 1) & 1);          // stage next (regs loaded last epoch)
            if (chunk < 6) LOADV(chunk + 2);  // issue loads for chunk+2 now
        }
        #pragma unroll
        for (int rt = 0; rt < 4; ++rt) {
            const ushort* sb = &Sx[bo + rt * 2048];
            bf16x8 a0 = *(const bf16x8*)&sb[fro[0]];
            bf16x8 a1 = *(const bf16x8*)&sb[fro[1]];
            bf16x8 a2 = *(const bf16x8*)&sb[fro[2]];
            bf16x8 a3 = *(const bf16x8*)&sb[fro[3]];
            f32x4 acc0 = {0.f,0.f,0.f,0.f}, acc1 = {0.f,0.f,0.f,0.f};
            acc0 = __builtin_amdgcn_mfma_f32_16x16x32_bf16(a0, bfr[0][0], acc0, 0, 0, 0);
            acc1 = __builtin_amdgcn_mfma_f32_16x16x32_bf16(a0, bfr[1][0], acc1, 0, 0, 0);
            acc0 = __builtin_amdgcn_mfma_f32_16x16x32_bf16(a1, bfr[0][1], acc0, 0, 0, 0);
            acc1 = __builtin_amdgcn_mfma_f32_16x16x32_bf16(a1, bfr[1][1], acc1, 0, 0, 0);
            acc0 = __builtin_amdgcn_mfma_f32_16x16x32_bf16(a2, bfr[0][2], acc0, 0, 0, 0);
            acc1 = __builtin_amdgcn_mfma_f32_16x16x32_bf16(a2, bfr[1][2], acc1, 0, 0, 0);
            acc0 = __builtin_amdgcn_mfma_f32_16x16x32_bf16(a3, bfr[0][3], acc0, 0, 0, 0);
            acc1 = __builtin_amdgcn_mfma_f32_16x16x32_bf16(a3, bfr[1][3], acc1, 0, 0, 0);

            int4 t4 = *(const int4*)&Tl[chunk * 64 + rt * 16 + quad * 4];
            int tvs[4] = {t4.x, t4.y, t4.z, t4.w};
            #pragma unroll
            for (int r = 0; r < 4; ++r) {
                { bool po = (tvs[r] == cls0); float v = acc0[r];
                  float e = __expf(po ? -ALPHA * (v - MRG) : ALPHA * (v + MRG));
                  pp0 += po ? e : 0.f; np0 += po ? 0.f : e; }
                { bool po = (tvs[r] == cls1); float v = acc1[r];
                  float e = __expf(po ? -ALPHA * (v - MRG) : ALPHA * (v + MRG));
                  pp1 += po ? e : 0.f; np1 += po ? 0.f : e; }
            }
        }
        __syncthreads();
    }
    #undef LOADV
    #undef WRITEV

    // ---- per-class totals across quads; adj factor; log1p (wave owns classes) --
    pp0 += __shfl_xor(pp0, 16); pp0 += __shfl_xor(pp0, 32);
    np0 += __shfl_xor(np0, 16); np0 += __shfl_xor(np0, 32);
    pp1 += __shfl_xor(pp1, 16); pp1 += __shfl_xor(pp1, 32);
    np1 += __shfl_xor(np1, 16); np1 += __shfl_xor(np1, 32);

    float lp = 0.f, ln = 0.f;
    {
        float a0 = adj[(cls0 < C) ? cls0 : C - 1];
        float a1 = adj[(cls1 < C) ? cls1 : C - 1];
        float as0 = (pp0 > 0.f) ? a0 : 0.f;     // absent class => adj = 0
        float as1 = (pp1 > 0.f) ? a1 : 0.f;
        if (cls0 < C) {
            lp += log1pf(pp0 * __expf(-ALPHA * as0));
            ln += log1pf(np0 * __expf( ALPHA * as0));
        }
        if (cls1 < C) {
            lp += log1pf(pp1 * __expf(-ALPHA * as1));
            ln += log1pf(np1 * __expf( ALPHA * as1));
        }
    }
    // quads hold identical values; sum across nlo
    #pragma unroll
    for (int off = 1; off < 16; off <<= 1) {
        lp += __shfl_xor(lp, off);
        ln += __shfl_xor(ln, off);
    }
    #pragma unroll
    for (int off = 1; off < 64; off <<= 1) cabs += __shfl_xor(cabs, off);

    if (lane == 0) { red[wv][0] = lp; red[wv][1] = ln; red[wv][2] = cabs; }
    __syncthreads();
    if (tid == 0) {
        atomicAdd(&scal[0], red[0][0] + red[1][0] + red[2][0] + red[3][0]);
        atomicAdd(&scal[1], red[0][1] + red[1][1] + red[2][1] + red[3][1]);
        atomicAdd(&scal[2], red[0][2] + red[1][2] + red[2][2] + red[3][2]);
        __threadfence();
        unsigned old = atomicAdd((unsigned*)(scal + 4), 1u);
        if (old == (unsigned)(nblk - 1)) {
            float S0 = atomicAdd(&scal[0], 0.f);
            float S1 = atomicAdd(&scal[1], 0.f);
            float S2 = atomicAdd(&scal[2], 0.f);
            float S3 = atomicAdd(&scal[3], 0.f);
            out[0] = S0 / S3 + S1 / (float)C + STAT_WEIGHT * (S2 / ((float)C * 128.f));
        }
    }
}

extern "C" void kernel_launch(void* const* d_in, const int* in_sizes, int n_in,
                              void* d_out, int out_size, void* d_ws, size_t ws_size,
                              hipStream_t stream) {
    const float* X       = (const float*)d_in[0];
    const int*   T       = (const int*)d_in[1];
    const float* proxies = (const float*)d_in[2];
    const float* cc      = (const float*)d_in[3];
    float* out = (float*)d_out;

    const int B = in_sizes[1];            // 512
    const int D = in_sizes[0] / B;        // 128
    const int C = in_sizes[2] / D;        // 50000

    float*  adj  = (float*)d_ws;                       // C (only present classes touched)
    float*  scal = adj + C;                            // 8 (zeroed)
    ushort* Xn16 = (ushort*)(scal + 8);                // B*D bf16, swizzled layout

    const int nblk = (C + 127) / 128;                  // 391

    (void)hipMemsetAsync(scal, 0, 8 * sizeof(float), stream);
    k_stats<<<B, 128, 0, stream>>>(X, proxies, cc, T, Xn16, adj, scal, B);
    k_main<<<nblk, 256, 0, stream>>>(proxies, cc, Xn16, T, adj, scal, out, C, nblk);
}